// Round 1
// baseline (496.277 us; speedup 1.0000x reference)
//
#include <hip/hip_runtime.h>
#include <math.h>

#define Bb 32
#define Nn 1024
#define Ee 4
#define Uu 32

// ---------------------------------------------------------------------------
// pre-kernel: h_pre_t[b][e][u][n] = sum_f ann[b,n,f]*Wa[e,f,u] + ba[e,u]
//             res[b][n][u]        = sum_f ann[b,n,f]*W2[f,u]  + b2[u]
// ann = concat(annA [B,N,FA], annB [B,N,F-FA])  (annB may be null when F==FA)
// h_pre stored TRANSPOSED (u-major, n-minor) so the main kernel's LDS staging
// is a linear conflict-free write; transpose here is free (coalesced along n).
// ---------------------------------------------------------------------------
template <int F, int FA>
__global__ __launch_bounds__(128) void pre_kernel(
    const float* __restrict__ annA, const float* __restrict__ annB,
    const float* __restrict__ Wa, const float* __restrict__ ba,
    const float* __restrict__ W2, const float* __restrict__ b2,
    float* __restrict__ hpre_t, float* __restrict__ res)
{
    __shared__ float wlds[5 * F * Uu];   // [e][f][u], e==4 -> W2
    __shared__ float blds[5 * Uu];       // [e][u],   e==4 -> b2
    const int tid = threadIdx.x;
    for (int i = tid; i < 4 * F * Uu; i += 128) wlds[i] = Wa[i];
    for (int i = tid; i < F * Uu; i += 128) wlds[4 * F * Uu + i] = W2[i];
    for (int i = tid; i < 4 * Uu; i += 128) blds[i] = ba[i];
    for (int i = tid; i < Uu; i += 128) blds[4 * Uu + i] = b2[i];
    __syncthreads();

    const int g = blockIdx.x * 128 + tid;   // flat row in [0, B*N)
    const int b = g >> 10;
    const int n = g & 1023;

    float4 a4[F / 4];
    {
        const float4* rA = (const float4*)(annA + (size_t)g * FA);
#pragma unroll
        for (int i = 0; i < FA / 4; ++i) a4[i] = rA[i];
        if constexpr (F > FA) {
            const float4* rB = (const float4*)(annB + (size_t)g * (F - FA));
#pragma unroll
            for (int i = 0; i < (F - FA) / 4; ++i) a4[FA / 4 + i] = rB[i];
        }
    }

    for (int e = 0; e < 5; ++e) {          // e==4 is the residual (W2/b2)
        float4 acc[8];
        const float4* bb = (const float4*)(blds + e * Uu);
#pragma unroll
        for (int uq = 0; uq < 8; ++uq) acc[uq] = bb[uq];
        const float4* w4 = (const float4*)wlds + (size_t)e * F * 8;
#pragma unroll
        for (int f4 = 0; f4 < F / 4; ++f4) {
            const float4 av = a4[f4];
#pragma unroll
            for (int c = 0; c < 4; ++c) {
                const float s = (c == 0) ? av.x : (c == 1) ? av.y : (c == 2) ? av.z : av.w;
#pragma unroll
                for (int uq = 0; uq < 8; ++uq) {
                    const float4 w = w4[(f4 * 4 + c) * 8 + uq];  // uniform addr -> broadcast
                    acc[uq].x = fmaf(s, w.x, acc[uq].x);
                    acc[uq].y = fmaf(s, w.y, acc[uq].y);
                    acc[uq].z = fmaf(s, w.z, acc[uq].z);
                    acc[uq].w = fmaf(s, w.w, acc[uq].w);
                }
            }
        }
        if (e < 4) {
            float* dst = hpre_t + ((size_t)(b * 4 + e) * Uu) * Nn + n;  // [b][e][u][n]
#pragma unroll
            for (int uq = 0; uq < 8; ++uq) {
                dst[(uq * 4 + 0) * Nn] = acc[uq].x;   // coalesced along n across lanes
                dst[(uq * 4 + 1) * Nn] = acc[uq].y;
                dst[(uq * 4 + 2) * Nn] = acc[uq].z;
                dst[(uq * 4 + 3) * Nn] = acc[uq].w;
            }
        } else {
            float4* dst = (float4*)(res + (size_t)g * Uu);
#pragma unroll
            for (int uq = 0; uq < 8; ++uq) dst[uq] = acc[uq];
        }
    }
}

// ---------------------------------------------------------------------------
// main kernel: out[b][n][u] = tanh( sum_e sum_m adj[b,e,n,m]*h_pre[b,e,m,u]
//                                   + res[b,n,u] )
// block = 256 thr (4 waves). Wave lane = gu(0..3: u-octet) x ms(0..15: m-slot).
// Each thread: acc[8 rows][8 u]. adj streamed global->VGPR as coalesced
// float4 (4x gu-duplication merges in cache). h chunk [32u][64m] staged in
// double-buffered LDS (transposed layout -> conflict-free b128 reads/writes).
// Epilogue: shfl_xor reduce over the 16 ms lanes, +residual, tanh, store.
// ---------------------------------------------------------------------------
__global__ __launch_bounds__(256) void gcn_main_kernel(
    const float* __restrict__ adj,     // [B,E,N,N]
    const float* __restrict__ hpre_t,  // [B,E,U,N]
    const float* __restrict__ res,     // [B,N,U]
    float* __restrict__ out)           // [B,N,U]
{
    __shared__ float hbuf[2][Uu * 64];    // 2 x 8 KiB, [u][m] within chunk

    const int bid = blockIdx.x;                       // 1024 blocks
    const int swz = (bid & 7) * 128 + (bid >> 3);     // XCD-aware, bijective (1024%8==0)
    const int b = swz >> 5;
    const int n0 = (swz & 31) * 32;
    const int tid = threadIdx.x;
    const int w = tid >> 6;
    const int lane = tid & 63;
    const int gu = lane >> 4;    // u-octet 0..3
    const int ms = lane & 15;    // m-slot 0..15
    const int wrow = n0 + w * 8;

    float acc[8][8];
#pragma unroll
    for (int r = 0; r < 8; ++r)
#pragma unroll
        for (int j = 0; j < 8; ++j) acc[r][j] = 0.f;

    const float* adjb = adj + (size_t)b * Ee * Nn * Nn;
    const float* hpb = hpre_t + (size_t)b * Ee * Uu * Nn;

    // staging assignment: flat float4 index fi covers chunk [u][16 float4 of m]
    const int fi0 = tid, fi1 = tid + 256;
    const int su0 = fi0 >> 4, sm0 = fi0 & 15;
    const int su1 = fi1 >> 4, sm1 = fi1 & 15;

    // prologue: load h chunk 0 (e=0, c=0)
    float4 hstage0 = *(const float4*)(hpb + (size_t)su0 * Nn + sm0 * 4);
    float4 hstage1 = *(const float4*)(hpb + (size_t)su1 * Nn + sm1 * 4);

    for (int it = 0; it < 64; ++it) {      // 4 e  x  16 chunks of 64 m
        const int e = it >> 4, c = it & 15;
        float* hb = hbuf[it & 1];

        // adj loads for this chunk: 8 rows x float4(4 m)
        const float* arow = adjb + ((size_t)e * Nn + wrow) * Nn + c * 64 + ms * 4;
        float4 av[8];
#pragma unroll
        for (int r = 0; r < 8; ++r) av[r] = *(const float4*)(arow + (size_t)r * Nn);

        // stage h chunk into LDS (linear -> conflict-free)
        ((float4*)hb)[fi0] = hstage0;
        ((float4*)hb)[fi1] = hstage1;

        // prefetch next h chunk
        if (it < 63) {
            const int e2 = (it + 1) >> 4, c2 = (it + 1) & 15;
            const float* hc = hpb + (size_t)e2 * Uu * Nn + c2 * 64;
            hstage0 = *(const float4*)(hc + (size_t)su0 * Nn + sm0 * 4);
            hstage1 = *(const float4*)(hc + (size_t)su1 * Nn + sm1 * 4);
        }
        __syncthreads();   // single barrier/iter is sufficient with double buffer

        // compute: acc[r][j] += dot(adj[row r, 4 m], h[u=gu*8+j, same 4 m])
#pragma unroll
        for (int j = 0; j < 8; ++j) {
            const float4 h = *(const float4*)(hb + (gu * 8 + j) * 64 + ms * 4);
#pragma unroll
            for (int r = 0; r < 8; ++r) {
                float t = fmaf(av[r].x, h.x, acc[r][j]);
                t = fmaf(av[r].y, h.y, t);
                t = fmaf(av[r].z, h.z, t);
                acc[r][j] = fmaf(av[r].w, h.w, t);
            }
        }
    }

    // reduce partial sums across the 16 m-slot lanes (low 4 lane bits)
#pragma unroll
    for (int r = 0; r < 8; ++r)
#pragma unroll
        for (int j = 0; j < 8; ++j) {
            float v = acc[r][j];
            v += __shfl_xor(v, 1);
            v += __shfl_xor(v, 2);
            v += __shfl_xor(v, 4);
            v += __shfl_xor(v, 8);
            acc[r][j] = v;
        }

    // epilogue: lane ms==r writes row wrow+r (static acc indexing via unroll)
#pragma unroll
    for (int r = 0; r < 8; ++r) {
        if (ms == r) {
            const int n = wrow + r;
            const float* rp = res + ((size_t)b * Nn + n) * Uu + gu * 8;
            float* op = out + ((size_t)b * Nn + n) * Uu + gu * 8;
            const float4 r0 = *(const float4*)(rp);
            const float4 r1 = *(const float4*)(rp + 4);
            float4 o0, o1;
            o0.x = tanhf(acc[r][0] + r0.x);
            o0.y = tanhf(acc[r][1] + r0.y);
            o0.z = tanhf(acc[r][2] + r0.z);
            o0.w = tanhf(acc[r][3] + r0.w);
            o1.x = tanhf(acc[r][4] + r1.x);
            o1.y = tanhf(acc[r][5] + r1.y);
            o1.z = tanhf(acc[r][6] + r1.z);
            o1.w = tanhf(acc[r][7] + r1.w);
            *(float4*)(op) = o0;
            *(float4*)(op + 4) = o1;
        }
    }
}

extern "C" void kernel_launch(void* const* d_in, const int* in_sizes, int n_in,
                              void* d_out, int out_size, void* d_ws, size_t ws_size,
                              hipStream_t stream)
{
    const float* n_tensor = (const float*)d_in[0];  // [32,1024,32]
    const float* adj      = (const float*)d_in[1];  // [32,4,1024,1024]
    const float* W_adj0   = (const float*)d_in[2];  // [4,32,32]
    const float* b_adj0   = (const float*)d_in[3];  // [4,32]
    const float* W2_0     = (const float*)d_in[4];  // [32,32]
    const float* b2_0     = (const float*)d_in[5];  // [32]
    const float* W_adj1   = (const float*)d_in[6];  // [4,64,32]
    const float* b_adj1   = (const float*)d_in[7];  // [4,32]
    const float* W2_1     = (const float*)d_in[8];  // [64,32]
    const float* b2_1     = (const float*)d_in[9];  // [32]
    float* outp = (float*)d_out;

    float* ws   = (float*)d_ws;
    float* hpre = ws;                        // 32*4*32*1024 = 4M floats (16 MiB)
    float* resb = ws + (size_t)4 * 1024 * 1024;  // 1M floats (4 MiB)
    float* h0   = ws + (size_t)5 * 1024 * 1024;  // 1M floats (4 MiB)

    // layer 0 (F = 32)
    pre_kernel<32, 32><<<256, 128, 0, stream>>>(n_tensor, nullptr, W_adj0, b_adj0,
                                                W2_0, b2_0, hpre, resb);
    gcn_main_kernel<<<1024, 256, 0, stream>>>(adj, hpre, resb, h0);

    // layer 1 (F = 64, ann = concat(n_tensor, h0))
    pre_kernel<64, 32><<<256, 128, 0, stream>>>(n_tensor, h0, W_adj1, b_adj1,
                                                W2_1, b2_1, hpre, resb);
    gcn_main_kernel<<<1024, 256, 0, stream>>>(adj, hpre, resb, outp);
}

// Round 2
// 426.887 us; speedup vs baseline: 1.1625x; 1.1625x over previous
//
#include <hip/hip_runtime.h>
#include <math.h>

#define Bb 32
#define Nn 1024
#define Ee 4
#define Uu 32

// ---------------------------------------------------------------------------
// pre-kernel: grid (128, 5), block 256. blockIdx.y = e (0..3 edge types,
// 4 = residual W2/b2). Each thread computes one row's 32 outputs for its e.
//   e<4 : hpre_t[b][e][u][n] = sum_f ann[b,n,f]*Wa[e,f,u] + ba[e,u]  (u-major!)
//   e==4: res[b][n][u]       = sum_f ann[b,n,f]*W2[f,u]  + b2[u]
// ann = concat(annA [B,N,FA], annB [B,N,F-FA]).
// ---------------------------------------------------------------------------
template <int F, int FA>
__global__ __launch_bounds__(256) void pre_kernel(
    const float* __restrict__ annA, const float* __restrict__ annB,
    const float* __restrict__ Wa, const float* __restrict__ ba,
    const float* __restrict__ W2, const float* __restrict__ b2,
    float* __restrict__ hpre_t, float* __restrict__ res)
{
    const int e = blockIdx.y;            // 0..4
    __shared__ float wlds[F * Uu];
    __shared__ float blds[Uu];
    const int tid = threadIdx.x;
    const float* wsrc = (e < 4) ? (Wa + (size_t)e * F * Uu) : W2;
    const float* bsrc = (e < 4) ? (ba + (size_t)e * Uu) : b2;
    for (int i = tid; i < F * Uu; i += 256) wlds[i] = wsrc[i];
    if (tid < Uu) blds[tid] = bsrc[tid];
    __syncthreads();

    const int g = blockIdx.x * 256 + tid;   // flat row in [0, B*N)
    const int b = g >> 10;
    const int n = g & 1023;

    float4 a4[F / 4];
    {
        const float4* rA = (const float4*)(annA + (size_t)g * FA);
#pragma unroll
        for (int i = 0; i < FA / 4; ++i) a4[i] = rA[i];
        if constexpr (F > FA) {
            const float4* rB = (const float4*)(annB + (size_t)g * (F - FA));
#pragma unroll
            for (int i = 0; i < (F - FA) / 4; ++i) a4[FA / 4 + i] = rB[i];
        }
    }

    float4 acc[8];
    const float4* bb = (const float4*)blds;
#pragma unroll
    for (int uq = 0; uq < 8; ++uq) acc[uq] = bb[uq];
    const float4* w4 = (const float4*)wlds;
#pragma unroll
    for (int f4 = 0; f4 < F / 4; ++f4) {
        const float4 av = a4[f4];
#pragma unroll
        for (int c = 0; c < 4; ++c) {
            const float s = (c == 0) ? av.x : (c == 1) ? av.y : (c == 2) ? av.z : av.w;
#pragma unroll
            for (int uq = 0; uq < 8; ++uq) {
                const float4 w = w4[(f4 * 4 + c) * 8 + uq];  // uniform -> broadcast
                acc[uq].x = fmaf(s, w.x, acc[uq].x);
                acc[uq].y = fmaf(s, w.y, acc[uq].y);
                acc[uq].z = fmaf(s, w.z, acc[uq].z);
                acc[uq].w = fmaf(s, w.w, acc[uq].w);
            }
        }
    }
    if (e < 4) {
        float* dst = hpre_t + ((size_t)(b * 4 + e) * Uu) * Nn + n;  // [b][e][u][n]
#pragma unroll
        for (int uq = 0; uq < 8; ++uq) {
            dst[(uq * 4 + 0) * Nn] = acc[uq].x;   // coalesced along n across lanes
            dst[(uq * 4 + 1) * Nn] = acc[uq].y;
            dst[(uq * 4 + 2) * Nn] = acc[uq].z;
            dst[(uq * 4 + 3) * Nn] = acc[uq].w;
        }
    } else {
        float4* dst = (float4*)(res + (size_t)g * Uu);
#pragma unroll
        for (int uq = 0; uq < 8; ++uq) dst[uq] = acc[uq];
    }
}

// ---------------------------------------------------------------------------
// main kernel: out[b][n][u] = tanh( sum_e sum_m adj[b,e,n,m]*h_pre[b,e,m,u]
//                                   + res[b,n,u] )
// Software-pipelined: adj for iter t+1 loads into the ALT register buffer and
// h for iter t+1 into hstage regs BEFORE the barrier; the barrier is a raw
// s_barrier with only lgkmcnt(0) (counted vmcnt survives the barrier), so
// global-load latency is hidden under the previous iteration's FMAs.
// ---------------------------------------------------------------------------
__global__ __launch_bounds__(256) void gcn_main_kernel(
    const float* __restrict__ adj,     // [B,E,N,N]
    const float* __restrict__ hpre_t,  // [B,E,U,N]
    const float* __restrict__ res,     // [B,N,U]
    float* __restrict__ out)           // [B,N,U]
{
    __shared__ float hbuf[2][Uu * 64];    // 2 x 8 KiB, [u][m] within chunk

    const int bid = blockIdx.x;                       // 1024 blocks
    const int swz = (bid & 7) * 128 + (bid >> 3);     // XCD-aware, bijective
    const int b = swz >> 5;
    const int n0 = (swz & 31) * 32;
    const int tid = threadIdx.x;
    const int w = tid >> 6;
    const int lane = tid & 63;
    const int gu = lane >> 4;    // u-octet 0..3
    const int ms = lane & 15;    // m-slot 0..15
    const int wrow = n0 + w * 8;

    float acc[8][8];
#pragma unroll
    for (int r = 0; r < 8; ++r)
#pragma unroll
        for (int j = 0; j < 8; ++j) acc[r][j] = 0.f;

    const float* adjb = adj + (size_t)b * Ee * Nn * Nn;
    const float* hpb = hpre_t + (size_t)b * Ee * Uu * Nn;

    const int fi0 = tid, fi1 = tid + 256;
    const int su0 = fi0 >> 4, sm0 = fi0 & 15;
    const int su1 = fi1 >> 4, sm1 = fi1 & 15;

    float4 adjA[8], adjB[8];
    float4 h0, h1;

    // prologue: issue adj(0) -> adjA and h(0) -> h0,h1
    {
        const float* ap = adjb + (size_t)wrow * Nn + ms * 4;
#pragma unroll
        for (int r = 0; r < 8; ++r) adjA[r] = *(const float4*)(ap + (size_t)r * Nn);
        h0 = *(const float4*)(hpb + (size_t)su0 * Nn + sm0 * 4);
        h1 = *(const float4*)(hpb + (size_t)su1 * Nn + sm1 * 4);
    }

    // Per iter t: [issue adj(t+1)->ALT] [issue h(t+1)->h0,h1 after ds_write of
    // h(t)] [lgkmcnt(0); s_barrier] [compute from CUR + hbuf[t&1]].
    // The compiler's auto-waitcnt resolves h(t)/adj(t) with COUNTED vmcnt
    // (the 10 iter-t+1 loads stay in flight across the barrier).
#define GCN_BODY(CUR, ALT, T)                                                   \
    {                                                                           \
        const int t_ = (T);                                                     \
        float* hb = hbuf[t_ & 1];                                               \
        ((float4*)hb)[fi0] = h0;   /* auto vmcnt wait for h(t) */               \
        ((float4*)hb)[fi1] = h1;                                                \
        const int tn_ = (t_ < 63) ? t_ + 1 : 63;                                \
        const int e2_ = tn_ >> 4, c2_ = tn_ & 15;                               \
        const float* ap_ = adjb + ((size_t)e2_ * Nn + wrow) * Nn + c2_ * 64 + ms * 4; \
        _Pragma("unroll")                                                       \
        for (int r = 0; r < 8; ++r) ALT[r] = *(const float4*)(ap_ + (size_t)r * Nn); \
        const float* hc_ = hpb + (size_t)e2_ * Uu * Nn + c2_ * 64;              \
        h0 = *(const float4*)(hc_ + (size_t)su0 * Nn + sm0 * 4);                \
        h1 = *(const float4*)(hc_ + (size_t)su1 * Nn + sm1 * 4);                \
        asm volatile("s_waitcnt lgkmcnt(0)" ::: "memory");                      \
        __builtin_amdgcn_s_barrier();                                           \
        __builtin_amdgcn_sched_barrier(0);                                      \
        _Pragma("unroll")                                                       \
        for (int j = 0; j < 8; ++j) {                                           \
            const float4 hv = *(const float4*)(hb + (gu * 8 + j) * 64 + ms * 4); \
            _Pragma("unroll")                                                   \
            for (int r = 0; r < 8; ++r) {                                       \
                float t = fmaf(CUR[r].x, hv.x, acc[r][j]);                      \
                t = fmaf(CUR[r].y, hv.y, t);                                    \
                t = fmaf(CUR[r].z, hv.z, t);                                    \
                acc[r][j] = fmaf(CUR[r].w, hv.w, t);                            \
            }                                                                   \
        }                                                                       \
    }

    for (int t = 0; t < 64; t += 2) {
        GCN_BODY(adjA, adjB, t);
        GCN_BODY(adjB, adjA, t + 1);
    }
#undef GCN_BODY

    // reduce partial sums across the 16 m-slot lanes (low 4 lane bits)
#pragma unroll
    for (int r = 0; r < 8; ++r)
#pragma unroll
        for (int j = 0; j < 8; ++j) {
            float v = acc[r][j];
            v += __shfl_xor(v, 1);
            v += __shfl_xor(v, 2);
            v += __shfl_xor(v, 4);
            v += __shfl_xor(v, 8);
            acc[r][j] = v;
        }

    // epilogue: lane ms==r writes row wrow+r
#pragma unroll
    for (int r = 0; r < 8; ++r) {
        if (ms == r) {
            const int n = wrow + r;
            const float* rp = res + ((size_t)b * Nn + n) * Uu + gu * 8;
            float* op = out + ((size_t)b * Nn + n) * Uu + gu * 8;
            const float4 r0 = *(const float4*)(rp);
            const float4 r1 = *(const float4*)(rp + 4);
            float4 o0, o1;
            o0.x = tanhf(acc[r][0] + r0.x);
            o0.y = tanhf(acc[r][1] + r0.y);
            o0.z = tanhf(acc[r][2] + r0.z);
            o0.w = tanhf(acc[r][3] + r0.w);
            o1.x = tanhf(acc[r][4] + r1.x);
            o1.y = tanhf(acc[r][5] + r1.y);
            o1.z = tanhf(acc[r][6] + r1.z);
            o1.w = tanhf(acc[r][7] + r1.w);
            *(float4*)(op) = o0;
            *(float4*)(op + 4) = o1;
        }
    }
}

extern "C" void kernel_launch(void* const* d_in, const int* in_sizes, int n_in,
                              void* d_out, int out_size, void* d_ws, size_t ws_size,
                              hipStream_t stream)
{
    const float* n_tensor = (const float*)d_in[0];  // [32,1024,32]
    const float* adj      = (const float*)d_in[1];  // [32,4,1024,1024]
    const float* W_adj0   = (const float*)d_in[2];  // [4,32,32]
    const float* b_adj0   = (const float*)d_in[3];  // [4,32]
    const float* W2_0     = (const float*)d_in[4];  // [32,32]
    const float* b2_0     = (const float*)d_in[5];  // [32]
    const float* W_adj1   = (const float*)d_in[6];  // [4,64,32]
    const float* b_adj1   = (const float*)d_in[7];  // [4,32]
    const float* W2_1     = (const float*)d_in[8];  // [64,32]
    const float* b2_1     = (const float*)d_in[9];  // [32]
    float* outp = (float*)d_out;

    float* ws   = (float*)d_ws;
    float* hpre = ws;                            // 16 MiB
    float* resb = ws + (size_t)4 * 1024 * 1024;  // 4 MiB
    float* h0   = ws + (size_t)5 * 1024 * 1024;  // 4 MiB

    dim3 pre_grid(128, 5);

    // layer 0 (F = 32)
    pre_kernel<32, 32><<<pre_grid, 256, 0, stream>>>(n_tensor, nullptr, W_adj0, b_adj0,
                                                     W2_0, b2_0, hpre, resb);
    gcn_main_kernel<<<1024, 256, 0, stream>>>(adj, hpre, resb, h0);

    // layer 1 (F = 64, ann = concat(n_tensor, h0))
    pre_kernel<64, 32><<<pre_grid, 256, 0, stream>>>(n_tensor, h0, W_adj1, b_adj1,
                                                     W2_1, b2_1, hpre, resb);
    gcn_main_kernel<<<1024, 256, 0, stream>>>(adj, hpre, resb, outp);
}